// Round 1
// baseline (298.945 us; speedup 1.0000x reference)
//
#include <hip/hip_runtime.h>

// Sizes from the reference: TAO=3, M=5, C_IN=7, D_MODEL=512
// KERNELS = 73, EXTRA = 1, warm = 15
#define S_LEN 4096
#define B_SZ 32
#define C_IN 7
#define D_MODEL 512
#define TL 64   // timesteps per block
#define NL 16   // timesteps per macro-iteration

// Interior FIR kernel: out[n,l,o] = b[o] + sum_d wf[o][d]*x[n, l-16+d, c(o)]
// valid for l in [16, 4094]; boundary rows overwritten by fixup kernel.
__global__ __launch_bounds__(512)
void fir_main(const float* __restrict__ x,
              const float* __restrict__ gw,  // (511, 6, 3)
              const float* __restrict__ gb,  // (511,)
              const float* __restrict__ lw,  // (1, 6, 3)
              const float* __restrict__ lb,  // (1,)
              float* __restrict__ out)       // (B, S, 512)
{
    const int o  = threadIdx.x;            // 0..511 output channel
    const int n  = blockIdx.x;             // batch
    const int l0 = blockIdx.y * TL;        // tile start

    const int c = (o < 511) ? (o / 73) : 6;
    const float* wsrc = (o < 511) ? (gw + o * 18) : lw;
    const float bias  = (o < 511) ? gb[o] : lb[0];

    // Flatten (j,k) -> FIR tap d = 15 + k - 3j  (bijective onto [0,18))
    float wf[18];
#pragma unroll
    for (int j = 0; j < 6; ++j)
#pragma unroll
        for (int k = 0; k < 3; ++k)
            wf[15 + k - 3 * j] = wsrc[j * 3 + k];

    const float* xc = x + (size_t)n * S_LEN * C_IN + c;     // stride C_IN in t
    float* op = out + ((size_t)n * S_LEN + l0) * D_MODEL + o;

#pragma unroll
    for (int mi = 0; mi < TL / NL; ++mi) {
        const int lb_ = l0 + mi * NL;   // first output l of this chunk
        // x window: x[lb_-16 .. lb_+NL], clamped (garbage only feeds
        // boundary rows which the fixup kernel overwrites)
        float xv[NL + 17];
#pragma unroll
        for (int d = 0; d < NL + 17; ++d) {
            int t = lb_ - 16 + d;
            t = t < 0 ? 0 : t;
            t = t > (S_LEN - 1) ? (S_LEN - 1) : t;
            xv[d] = xc[(size_t)t * C_IN];
        }
#pragma unroll
        for (int u = 0; u < NL; ++u) {
            float acc = bias;
#pragma unroll
            for (int d = 0; d < 18; ++d)
                acc = fmaf(wf[d], xv[u + d], acc);
            op[(size_t)(mi * NL + u) * D_MODEL] = acc;
        }
    }
}

// General-formula fixup for l in [0,15] and l = S-1 (wrap + warm-up zeros).
__global__ __launch_bounds__(512)
void fir_fixup(const float* __restrict__ x,
               const float* __restrict__ gw,
               const float* __restrict__ gb,
               const float* __restrict__ lw,
               const float* __restrict__ lb,
               float* __restrict__ out)
{
    const int o  = threadIdx.x;
    const int n  = blockIdx.x;
    const int li = blockIdx.y;                 // 0..16
    const int l  = (li < 16) ? li : (S_LEN - 1);

    const int c = (o < 511) ? (o / 73) : 6;
    const float* wsrc = (o < 511) ? (gw + o * 18) : lw;
    float acc = (o < 511) ? gb[o] : lb[0];

    const float* xc = x + (size_t)n * S_LEN * C_IN + c;
#pragma unroll
    for (int j = 0; j < 6; ++j) {
#pragma unroll
        for (int k = 0; k < 3; ++k) {
            int t = l - 1 + k;
            if (t < 0) t += S_LEN;
            if (t >= S_LEN) t -= S_LEN;
            if (t >= 15)  // warm-up rows are zero
                acc = fmaf(wsrc[j * 3 + k], xc[(size_t)(t - 3 * j) * C_IN], acc);
        }
    }
    out[((size_t)n * S_LEN + l) * D_MODEL + o] = acc;
}

extern "C" void kernel_launch(void* const* d_in, const int* in_sizes, int n_in,
                              void* d_out, int out_size, void* d_ws, size_t ws_size,
                              hipStream_t stream)
{
    const float* x  = (const float*)d_in[0];  // (32, 4096, 7)
    const float* gw = (const float*)d_in[1];  // (511, 6, 3)
    const float* gb = (const float*)d_in[2];  // (511,)
    const float* lw = (const float*)d_in[3];  // (1, 6, 3)
    const float* lb = (const float*)d_in[4];  // (1,)
    float* out = (float*)d_out;               // (32, 4096, 512)

    dim3 grid_main(B_SZ, S_LEN / TL);         // (32, 64)
    fir_main<<<grid_main, 512, 0, stream>>>(x, gw, gb, lw, lb, out);

    dim3 grid_fix(B_SZ, 17);                  // l in [0,15] and 4095
    fir_fixup<<<grid_fix, 512, 0, stream>>>(x, gw, gb, lw, lb, out);
}

// Round 5
// 284.501 us; speedup vs baseline: 1.0508x; 1.0508x over previous
//
#include <hip/hip_runtime.h>

// TAO=3, M=5, C_IN=7, D_MODEL=512 -> KERNELS=73, EXTRA=1, warm=15
// Interior identity: out[n,l,o] = b[o] + sum_{d<18} wf[o][d] * x[n, l-16+d, c(o)]
// with wf[15+k-3j] = w[o][j][k]; valid for l in [16, 4094].
#define S_LEN 4096
#define B_SZ 32
#define C_IN 7
#define D_MODEL 512
#define TL 64    // timesteps per block
#define CH 8     // outputs per chunk
#define NCH (TL / CH)

__global__ __launch_bounds__(512)
void fir_main(const float* __restrict__ x,
              const float* __restrict__ gw,   // (511, 6, 3)
              const float* __restrict__ gb,   // (511,)
              const float* __restrict__ lw,   // (1, 6, 3)
              const float* __restrict__ lb,   // (1,)
              float* __restrict__ out)        // (B, S, 512)
{
    __shared__ float ws[512 * 18];   // 36 KB, weights in (o,j,k) layout
    __shared__ float wb[512];        // 2 KB bias
    __shared__ float xs[7][88];      // x window, [c][t_local], rows 16B-aligned

    const int tid = threadIdx.x;
    const int n   = blockIdx.x;
    const int l0  = blockIdx.y * TL;

    // ---- stage weights, coalesced ----
    for (int i = tid; i < 512 * 18; i += 512)
        ws[i] = (i < 511 * 18) ? gw[i] : lw[i - 511 * 18];
    wb[tid] = (tid < 511) ? gb[tid] : lb[0];

    // ---- stage x window: global t = l0-16 .. l0+64 (81 steps, clamped) ----
    for (int i = tid; i < 81 * 7; i += 512) {
        int t = i / 7, c = i - t * 7;
        int tg = l0 - 16 + t;
        tg = tg < 0 ? 0 : (tg > S_LEN - 1 ? S_LEN - 1 : tg);
        xs[c][t] = x[((size_t)n * S_LEN + tg) * C_IN + c];
    }
    __syncthreads();

    // ---- per-thread weights -> registers, permuted to FIR taps ----
    const int o = tid;
    const int c = (o < 511) ? (o / 73) : 6;
    float wf[18];
#pragma unroll
    for (int j = 0; j < 6; ++j)
#pragma unroll
        for (int k = 0; k < 3; ++k)
            wf[15 + k - 3 * j] = ws[o * 18 + j * 3 + k];
    const float bias = wb[o];

    float* op = out + ((size_t)n * S_LEN + l0) * D_MODEL + o;

#pragma unroll
    for (int ci = 0; ci < NCH; ++ci) {
        // x local window for outputs l0+ci*8 .. +7: indices [ci*8, ci*8+24]
        float xv[28];
        const float* xb = &xs[c][ci * CH];   // 16B-aligned (CH*4B = 32B)
#pragma unroll
        for (int q = 0; q < 7; ++q) {
            float4 v = *(const float4*)(xb + q * 4);
            xv[q * 4 + 0] = v.x; xv[q * 4 + 1] = v.y;
            xv[q * 4 + 2] = v.z; xv[q * 4 + 3] = v.w;
        }
#pragma unroll
        for (int u = 0; u < CH; ++u) {
            float acc = bias;
#pragma unroll
            for (int d = 0; d < 18; ++d)
                acc = fmaf(wf[d], xv[u + d], acc);
            op[(size_t)(ci * CH + u) * D_MODEL] = acc;
        }
    }
}

// General-formula fixup for l in [0,15] and l = S-1 (wrap + warm-up zeros).
__global__ __launch_bounds__(512)
void fir_fixup(const float* __restrict__ x,
               const float* __restrict__ gw,
               const float* __restrict__ gb,
               const float* __restrict__ lw,
               const float* __restrict__ lb,
               float* __restrict__ out)
{
    const int o  = threadIdx.x;
    const int n  = blockIdx.x;
    const int li = blockIdx.y;                 // 0..16
    const int l  = (li < 16) ? li : (S_LEN - 1);

    const int c = (o < 511) ? (o / 73) : 6;
    const float* wsrc = (o < 511) ? (gw + o * 18) : lw;
    float acc = (o < 511) ? gb[o] : lb[0];

    const float* xc = x + (size_t)n * S_LEN * C_IN + c;
#pragma unroll
    for (int j = 0; j < 6; ++j) {
#pragma unroll
        for (int k = 0; k < 3; ++k) {
            int t = l - 1 + k;
            if (t < 0) t += S_LEN;
            if (t >= S_LEN) t -= S_LEN;
            if (t >= 15)  // warm-up rows are zero
                acc = fmaf(wsrc[j * 3 + k], xc[(size_t)(t - 3 * j) * C_IN], acc);
        }
    }
    out[((size_t)n * S_LEN + l) * D_MODEL + o] = acc;
}

extern "C" void kernel_launch(void* const* d_in, const int* in_sizes, int n_in,
                              void* d_out, int out_size, void* d_ws, size_t ws_size,
                              hipStream_t stream)
{
    const float* x  = (const float*)d_in[0];  // (32, 4096, 7)
    const float* gw = (const float*)d_in[1];  // (511, 6, 3)
    const float* gb = (const float*)d_in[2];  // (511,)
    const float* lw = (const float*)d_in[3];  // (1, 6, 3)
    const float* lb = (const float*)d_in[4];  // (1,)
    float* out = (float*)d_out;               // (B, S, 512)

    dim3 grid_main(B_SZ, S_LEN / TL);         // (32, 64)
    fir_main<<<grid_main, 512, 0, stream>>>(x, gw, gb, lw, lb, out);

    dim3 grid_fix(B_SZ, 17);                  // l in [0,15] and 4095
    fir_fixup<<<grid_fix, 512, 0, stream>>>(x, gw, gb, lw, lb, out);
}

// Round 7
// 278.352 us; speedup vs baseline: 1.0740x; 1.0221x over previous
//
#include <hip/hip_runtime.h>

// TAO=3, M=5, C_IN=7, D_MODEL=512 -> KERNELS=73, EXTRA=1, warm=15
// Interior identity (valid l in [16,4094]):
//   out[n,l,o] = b[o] + sum_{d<18} wf[o][d] * x[n, l-16+d, c(o)],
//   wf[15+k-3j] = w[o][j][k].
// Boundary rows (l<16, l=4095) use the general wrap formula, fused below.
#define S_LEN 4096
#define B_SZ 32
#define C_IN 7
#define D_MODEL 512
#define TL 128              // timesteps per block
#define CH 8                // outputs per chunk
#define NCH (TL / CH)       // 16
#define WIN (TL + 17)       // 145 staged x timesteps
#define XROW 148            // padded row: 592B = 16B-aligned; 148%32=20 -> banks spread

__global__ __launch_bounds__(512)
void fir_fused(const float* __restrict__ x,
               const float* __restrict__ gw,   // (511, 6, 3)
               const float* __restrict__ gb,   // (511,)
               const float* __restrict__ lw,   // (1, 6, 3)
               const float* __restrict__ lb,   // (1,)
               float* __restrict__ out)        // (B, S, 512)
{
    __shared__ float ws[512 * 18];   // 36 KB weights, (o,j,k) layout
    __shared__ float xs[7][XROW];    // 4.1 KB x window [c][t_local]

    const int tid = threadIdx.x;
    const int n   = blockIdx.x;
    const int by  = blockIdx.y;
    const int l0  = by * TL;

    // ---- stage weights, coalesced ----
    for (int i = tid; i < 512 * 18; i += 512)
        ws[i] = (i < 511 * 18) ? gw[i] : lw[i - 511 * 18];

    // ---- stage x window: t = l0-16 .. l0+TL (145 steps, clamped) ----
    // i runs over (t,c) pairs contiguously == contiguous global memory.
    for (int i = tid; i < WIN * C_IN; i += 512) {
        int t = i / 7, c = i - t * 7;
        int tg = l0 - 16 + t;
        tg = tg < 0 ? 0 : (tg > S_LEN - 1 ? S_LEN - 1 : tg);
        xs[c][t] = x[((size_t)n * S_LEN + tg) * C_IN + c];
    }
    __syncthreads();

    // ---- per-thread weights -> registers, permuted to FIR taps ----
    const int o = tid;
    const int c = (o < 511) ? (o / 73) : 6;
    float wf[18];
#pragma unroll
    for (int j = 0; j < 6; ++j)
#pragma unroll
        for (int k = 0; k < 3; ++k)
            wf[15 + k - 3 * j] = ws[o * 18 + j * 3 + k];
    const float bias = (o < 511) ? gb[o] : lb[0];

    float* op = out + ((size_t)n * S_LEN + l0) * D_MODEL + o;

    // ---- interior FIR ----
#pragma unroll
    for (int ci = 0; ci < NCH; ++ci) {
        float xv[28];                        // need ci*8 .. ci*8+24; load 28
        const float* xb = &xs[c][ci * CH];   // 16B-aligned (rows 592B, CH*4=32B)
#pragma unroll
        for (int q = 0; q < 7; ++q) {
            float4 v = *(const float4*)(xb + q * 4);
            xv[q * 4 + 0] = v.x; xv[q * 4 + 1] = v.y;
            xv[q * 4 + 2] = v.z; xv[q * 4 + 3] = v.w;
        }
#pragma unroll
        for (int u = 0; u < CH; ++u) {
            float acc = bias;
#pragma unroll
            for (int d = 0; d < 18; ++d)
                acc = fmaf(wf[d], xv[u + d], acc);
            op[(size_t)(ci * CH + u) * D_MODEL] = acc;
        }
    }

    // ---- fused boundary fixup (overwrites the garbage interior results) ----
    if (by == 0) {
        // rows l = 0..15: wrap + warm-up-zero general formula
#pragma unroll 1
        for (int l = 0; l < 16; ++l) {
            float acc = bias;
#pragma unroll
            for (int j = 0; j < 6; ++j)
#pragma unroll
                for (int k = 0; k < 3; ++k) {
                    int t = l - 1 + k;
                    if (t < 0) t += S_LEN;
                    if (t >= 15)   // warm-up rows of the gather are zero
                        acc = fmaf(ws[o * 18 + j * 3 + k],
                                   x[((size_t)n * S_LEN + (t - 3 * j)) * C_IN + c],
                                   acc);
                }
            out[((size_t)n * S_LEN + l) * D_MODEL + o] = acc;
        }
    } else if (by == (S_LEN / TL) - 1) {
        // row l = 4095: k=2 wraps to t=0 (<15 -> dropped)
        const int l = S_LEN - 1;
        float acc = bias;
#pragma unroll
        for (int j = 0; j < 6; ++j)
#pragma unroll
            for (int k = 0; k < 3; ++k) {
                int t = l - 1 + k;
                if (t >= S_LEN) t -= S_LEN;
                if (t >= 15)
                    acc = fmaf(ws[o * 18 + j * 3 + k],
                               x[((size_t)n * S_LEN + (t - 3 * j)) * C_IN + c],
                               acc);
            }
        out[((size_t)n * S_LEN + l) * D_MODEL + o] = acc;
    }
}

extern "C" void kernel_launch(void* const* d_in, const int* in_sizes, int n_in,
                              void* d_out, int out_size, void* d_ws, size_t ws_size,
                              hipStream_t stream)
{
    const float* x  = (const float*)d_in[0];  // (32, 4096, 7)
    const float* gw = (const float*)d_in[1];  // (511, 6, 3)
    const float* gb = (const float*)d_in[2];  // (511,)
    const float* lw = (const float*)d_in[3];  // (1, 6, 3)
    const float* lb = (const float*)d_in[4];  // (1,)
    float* out = (float*)d_out;               // (B, S, 512)

    dim3 grid(B_SZ, S_LEN / TL);              // (32, 32) — single dispatch
    fir_fused<<<grid, 512, 0, stream>>>(x, gw, gb, lw, lb, out);
}

// Round 10
// 274.623 us; speedup vs baseline: 1.0886x; 1.0136x over previous
//
#include <hip/hip_runtime.h>

// TAO=3, M=5, C_IN=7, D_MODEL=512 -> KERNELS=73, EXTRA=1, warm=15
// Interior identity (valid l in [16,4094]):
//   out[n,l,o] = b[o] + sum_{d<18} wf[o][d] * x[n, l-16+d, c(o)],
//   wf[15+k-3j] = w[o][j][k].
// Boundary rows (l<16, l=4095) use the general wrap formula, fused below.
#define S_LEN 4096
#define B_SZ 32
#define C_IN 7
#define D_MODEL 512
#define TL 128              // timesteps per block
#define CH 8                // outputs per chunk
#define NCH (TL / CH)       // 16
#define WIN (TL + 17)       // 145 staged x timesteps
#define XROW 148            // padded row: 592B = 16B-aligned; 148%32=20 -> banks spread

__global__ __launch_bounds__(512)
void fir_fused(const float* __restrict__ x,
               const float* __restrict__ gw,   // (511, 6, 3)
               const float* __restrict__ gb,   // (511,)
               const float* __restrict__ lw,   // (1, 6, 3)
               const float* __restrict__ lb,   // (1,)
               float* __restrict__ out)        // (B, S, 512)
{
    __shared__ float xs[7][XROW];    // 4.1 KB x window [c][t_local] — only LDS

    const int tid = threadIdx.x;
    const int n   = blockIdx.x;
    const int by  = blockIdx.y;
    const int l0  = by * TL;

    // ---- stage x window: t = l0-16 .. l0+TL (145 steps, clamped) ----
    for (int i = tid; i < WIN * C_IN; i += 512) {
        int t = i / 7, c = i - t * 7;
        int tg = l0 - 16 + t;
        tg = tg < 0 ? 0 : (tg > S_LEN - 1 ? S_LEN - 1 : tg);
        xs[c][t] = x[((size_t)n * S_LEN + tg) * C_IN + c];
    }

    // ---- weights straight to registers (L1/L2-resident, 72B rows, 8B-aligned) ----
    const int o = tid;
    const int c = (o < 511) ? (o / 73) : 6;
    const float* wsrc = (o < 511) ? (gw + o * 18) : lw;
    float wraw[18];
#pragma unroll
    for (int q = 0; q < 9; ++q) {
        float2 v = *(const float2*)(wsrc + q * 2);
        wraw[q * 2] = v.x; wraw[q * 2 + 1] = v.y;
    }
    float wf[18];
#pragma unroll
    for (int j = 0; j < 6; ++j)
#pragma unroll
        for (int k = 0; k < 3; ++k)
            wf[15 + k - 3 * j] = wraw[j * 3 + k];   // FIR-tap permutation
    const float bias = (o < 511) ? gb[o] : lb[0];

    __syncthreads();

    float* op = out + ((size_t)n * S_LEN + l0) * D_MODEL + o;

    // ---- interior FIR ----
#pragma unroll
    for (int ci = 0; ci < NCH; ++ci) {
        float xv[28];                        // need ci*8 .. ci*8+24; load 28
        const float* xb = &xs[c][ci * CH];   // 16B-aligned (rows 592B, CH*4=32B)
#pragma unroll
        for (int q = 0; q < 7; ++q) {
            float4 v = *(const float4*)(xb + q * 4);
            xv[q * 4 + 0] = v.x; xv[q * 4 + 1] = v.y;
            xv[q * 4 + 2] = v.z; xv[q * 4 + 3] = v.w;
        }
#pragma unroll
        for (int u = 0; u < CH; ++u) {
            float acc = bias;
#pragma unroll
            for (int d = 0; d < 18; ++d)
                acc = fmaf(wf[d], xv[u + d], acc);
            op[(size_t)(ci * CH + u) * D_MODEL] = acc;
        }
    }

    // ---- fused boundary fixup (overwrites the garbage interior results) ----
    if (by == 0) {
        // rows l = 0..15: wrap + warm-up-zero general formula
#pragma unroll 1
        for (int l = 0; l < 16; ++l) {
            float acc = bias;
#pragma unroll
            for (int j = 0; j < 6; ++j)
#pragma unroll
                for (int k = 0; k < 3; ++k) {
                    int t = l - 1 + k;
                    if (t < 0) t += S_LEN;
                    if (t >= 15)   // warm-up rows of the gather are zero
                        acc = fmaf(wf[15 + k - 3 * j],
                                   x[((size_t)n * S_LEN + (t - 3 * j)) * C_IN + c],
                                   acc);
                }
            out[((size_t)n * S_LEN + l) * D_MODEL + o] = acc;
        }
    } else if (by == (S_LEN / TL) - 1) {
        // row l = 4095: k=2 wraps to t=0 (<15 -> dropped)
        const int l = S_LEN - 1;
        float acc = bias;
#pragma unroll
        for (int j = 0; j < 6; ++j)
#pragma unroll
            for (int k = 0; k < 3; ++k) {
                int t = l - 1 + k;
                if (t >= S_LEN) t -= S_LEN;
                if (t >= 15)
                    acc = fmaf(wf[15 + k - 3 * j],
                               x[((size_t)n * S_LEN + (t - 3 * j)) * C_IN + c],
                               acc);
            }
        out[((size_t)n * S_LEN + l) * D_MODEL + o] = acc;
    }
}

extern "C" void kernel_launch(void* const* d_in, const int* in_sizes, int n_in,
                              void* d_out, int out_size, void* d_ws, size_t ws_size,
                              hipStream_t stream)
{
    const float* x  = (const float*)d_in[0];  // (32, 4096, 7)
    const float* gw = (const float*)d_in[1];  // (511, 6, 3)
    const float* gb = (const float*)d_in[2];  // (511,)
    const float* lw = (const float*)d_in[3];  // (1, 6, 3)
    const float* lb = (const float*)d_in[4];  // (1,)
    float* out = (float*)d_out;               // (B, S, 512)

    dim3 grid(B_SZ, S_LEN / TL);              // (32, 32) — single dispatch
    fir_fused<<<grid, 512, 0, stream>>>(x, gw, gb, lw, lb, out);
}